// Round 6
// baseline (92.766 us; speedup 1.0000x reference)
//
#include <hip/hip_runtime.h>
#include <cstdint>
#include <cstddef>

__device__ static const int   d_GOV[66] = {
  21,21, 9,12, 9,12,17,17,17,17,15,16,15,16, 8, 8,11, 8,14, 7,14, 7,
  13,13,13,13,15,15,15,15,10,10,10,10, 4, 3, 4, 3, 1, 1, 1, 1, 6, 6,
   6, 6,18,18,18,18, 0,20, 0,20,16,16,16,16, 0, 2,19, 2,10, 5,10, 5};
__device__ static const float d_NSYN[66] = {
  0,0, 2,2,2,2, 4,4,4,4, 6,6,6,6, 3,3,1,3, 2,2,2,2, 4,4,4,4,
  6,6,6,6, 6,6,6,6, 2,2,2,2, 4,4,4,4, 4,4,4,4, 4,4,4,4,
  3,2,3,2, 6,6,6,6, 3,2,1,2, 6,2,6,2};

__device__ __forceinline__ void gload_lds16(const void* g, void* l) {
  __builtin_amdgcn_global_load_lds(
      (const __attribute__((address_space(1))) void*)g,
      (__attribute__((address_space(3))) void*)l, 16, 0, 0);
}
__device__ __forceinline__ void gload_lds4(const void* g, void* l) {
  __builtin_amdgcn_global_load_lds(
      (const __attribute__((address_space(1))) void*)g,
      (__attribute__((address_space(3))) void*)l, 4, 0, 0);
}

// k_pos: 1-wave blocks, 8 rounds x 32 positions, 2 lanes per position.
// Small double-buffered LDS (17.3 KB total -> 9 blocks/CU) + per-wave
// issue-next/compute-current/drain pipeline. Per-lane state: 17 float2.
__global__ __launch_bounds__(64) void k_pos(
    const float* __restrict__ logits,
    const float* __restrict__ W,
    const int* __restrict__ tgt,
    const int* __restrict__ species,
    const unsigned char* __restrict__ mask,
    float* __restrict__ ws,
    int B, int L)
{
  const int lane = threadIdx.x;            // 0..63
  const int blk  = blockIdx.x;
  const int bpr  = L >> 8;                 // 256 positions per block
  const int b    = blk / bpr;
  const size_t base = (size_t)blk * 256;

  __shared__ float sbuf[2][2112];          // 2 x 8448 B
  __shared__ float s_logw[66];
  __shared__ int   s_cnt[132];             // [0..65]=pred, [66..131]=tgt

  {
    const int s = species[b];
    s_logw[lane] = __logf(fmaxf(W[s * 66 + lane], 1e-8f));
    if (lane < 2) s_logw[64 + lane] = __logf(fmaxf(W[s * 66 + 64 + lane], 1e-8f));
  }
  s_cnt[lane] = 0; s_cnt[64 + lane] = 0;
  if (lane < 4) s_cnt[128 + lane] = 0;
  __syncthreads();

  // stage round 0 into buf0: 32 pos x 264 B = 8448 B = 8 x 1024 + 256 tail
  {
    const float* g = logits + base * 66;
    #pragma unroll
    for (int i = 0; i < 8; ++i)
      gload_lds16(g + (size_t)(i * 64 + lane) * 4, (char*)sbuf[0] + (size_t)i * 1024);
    gload_lds4(g + 2048 + lane, (char*)sbuf[0] + 8192);
  }
  asm volatile("s_waitcnt vmcnt(0)" ::: "memory");

  const int p  = lane >> 1;                // position within round (0..31)
  const int hi = lane & 1;                 // 0: k in [0,32), 1: k in [32,66)
  float acc0 = 0.f, acc1 = 0.f, acc2 = 0.f, acc3 = 0.f, acc4 = 0.f;

  #pragma unroll 2
  for (int r = 0; r < 8; ++r) {
    // tgt/mask for this round (issued BEFORE prefetch so their auto-waitcnt
    // leaves the prefetch loads outstanding)
    int tg32 = 0; float mk32 = 0.0f;
    if (lane < 32) {
      const size_t pos = base + (size_t)r * 32 + lane;
      tg32 = tgt[pos];
      mk32 = mask[pos] ? 1.0f : 0.0f;
    }

    // issue next round's prefetch into the other buffer
    if (r < 7) {
      const float* g = logits + (base + (size_t)(r + 1) * 32) * 66;
      char* d = (char*)sbuf[(r + 1) & 1];
      #pragma unroll
      for (int i = 0; i < 8; ++i)
        gload_lds16(g + (size_t)(i * 64 + lane) * 4, d + (size_t)i * 1024);
      gload_lds4(g + 2048 + lane, d + 8192);
    }

    // compute current buffer: lane pair (2p, 2p+1) shares position p
    const float* row = &sbuf[r & 1][p * 66 + hi * 32];
    const int nj = hi ? 17 : 16;           // float2 count (32 or 34 floats)
    float2 w[17];
    #pragma unroll
    for (int j = 0; j < 17; ++j) if (j < nj) w[j] = ((const float2*)row)[j];

    float m = -3.4e38f; int ki = 0;
    #pragma unroll
    for (int j = 0; j < 17; ++j) if (j < nj) {
      const int k0 = hi * 32 + 2 * j;
      if (w[j].x > m) { m = w[j].x; ki = k0; }
      if (w[j].y > m) { m = w[j].y; ki = k0 + 1; }
    }
    // combine pair; ties -> smaller index (even lane holds lower ks)
    {
      float om = __shfl_xor(m, 1);
      int   oi = __shfl_xor(ki, 1);
      if (om > m || (om == m && oi < ki)) { m = om; ki = oi; }
    }

    const int   tg = __shfl(tg32, p);      // broadcast from loader lane p
    const float mk = __shfl(mk32, p);

    float se = 0.f, xt = 0.f;
    #pragma unroll
    for (int j = 0; j < 17; ++j) if (j < nj) {
      const int k0 = hi * 32 + 2 * j;
      se += __expf(w[j].x - m);
      se += __expf(w[j].y - m);
      if (k0 == tg)     xt = w[j].x;
      if (k0 + 1 == tg) xt = w[j].y;
    }
    se += __shfl_xor(se, 1);
    xt += __shfl_xor(xt, 1);

    if (hi == 0) {
      const float nll = __logf(se) + m - xt;
      if (tg != 0) { acc0 += nll; acc1 += 1.0f; }
      acc2 += s_logw[ki] * mk;
      acc3 += s_logw[tg] * mk;
      acc4 += mk;
      if (mk != 0.0f) {
        if (ki >= 2) atomicAdd(&s_cnt[ki], 1);
        if (tg >= 2) atomicAdd(&s_cnt[66 + tg], 1);
      }
    }

    // drain this round's prefetch (covered by the compute above)
    asm volatile("s_waitcnt vmcnt(0) lgkmcnt(0)" ::: "memory");
  }

  // wave reduction + global flush
  #pragma unroll
  for (int off = 32; off > 0; off >>= 1) {
    acc0 += __shfl_xor(acc0, off);
    acc1 += __shfl_xor(acc1, off);
    acc2 += __shfl_xor(acc2, off);
    acc3 += __shfl_xor(acc3, off);
    acc4 += __shfl_xor(acc4, off);
  }
  int* wsi = (int*)ws;
  const int off_slp = 2, off_slt = 2 + B, off_mc = 2 + 2 * B, off_cp = 2 + 3 * B;
  const int off_ct = off_cp + B * 66;
  if (lane == 0) {
    atomicAdd(&ws[0], acc0);
    atomicAdd(&ws[1], acc1);
    atomicAdd(&ws[off_slp + b], acc2);
    atomicAdd(&ws[off_slt + b], acc3);
    atomicAdd(&ws[off_mc + b], acc4);
  }
  __syncthreads();
  for (int j = lane; j < 132; j += 64) {
    const int val = s_cnt[j];
    if (val != 0) {
      if (j < 66) atomicAdd(&wsi[off_cp + b * 66 + j], val);
      else        atomicAdd(&wsi[off_ct + b * 66 + (j - 66)], val);
    }
  }
}

// Kernel 2: per-row CAI + RSCU-KL, codon-parallel. Grid: B blocks x 128 threads.
__global__ __launch_bounds__(128) void k_row(
    const float* __restrict__ refd,
    const int* __restrict__ species,
    float* __restrict__ ws,
    int B)
{
  const int b    = blockIdx.x;
  const int tid  = threadIdx.x;
  const int lane = tid & 63;
  const int wave = tid >> 6;
  const int off_slp = 2, off_slt = 2 + B, off_mc = 2 + 2 * B, off_cp = 2 + 3 * B;
  const int off_ct = off_cp + B * 66;
  const int off_res = off_ct + B * 66;
  const int* wsi = (const int*)ws;

  __shared__ float gp[24], gt[24];
  __shared__ float red[8];
  if (tid < 24) { gp[tid] = 0.0f; gt[tid] = 0.0f; }
  __syncthreads();

  float cp = 0.0f, ct = 0.0f, nsyn = 0.0f, ref = 0.0f;
  int gov = 22;
  if (tid < 66) {
    cp = (float)wsi[off_cp + b * 66 + tid];
    ct = (float)wsi[off_ct + b * 66 + tid];
    gov  = d_GOV[tid];
    nsyn = d_NSYN[tid];
    ref  = refd[species[b] * 66 + tid];
    atomicAdd(&gp[gov], cp);   // integer-valued floats: order-independent exact
    atomicAdd(&gt[gov], ct);
  }
  __syncthreads();

  float rp = 0.0f, rt = 0.0f;
  if (tid < 66) {
    float g1 = gp[gov]; rp = (g1 > 0.0f) ? cp * nsyn / g1 : 0.0f;
    float g2 = gt[gov]; rt = (g2 > 0.0f) ? ct * nsyn / g2 : 0.0f;
  }
  float pp = (tid < 66) ? (rp + 1e-8f) : 0.0f;
  float tp = (tid < 66) ? (0.7f * rt + 0.3f * ref + 1e-8f) : 0.0f;
  #pragma unroll
  for (int off = 32; off > 0; off >>= 1) {
    pp += __shfl_xor(pp, off);
    tp += __shfl_xor(tp, off);
  }
  if (lane == 0) { red[wave * 2] = pp; red[wave * 2 + 1] = tp; }
  __syncthreads();
  const float psum = red[0] + red[2];
  const float tsum = red[1] + red[3];

  float kl = 0.0f;
  if (tid < 66) {
    float pv = (rp + 1e-8f) / psum;
    float tv = (0.7f * rt + 0.3f * ref + 1e-8f) / tsum;
    kl = tv * __logf(tv / pv);
  }
  #pragma unroll
  for (int off = 32; off > 0; off >>= 1) kl += __shfl_xor(kl, off);
  if (lane == 0) red[4 + wave] = kl;
  __syncthreads();

  if (tid == 0) {
    float klt = red[4] + red[5];
    float mc    = fmaxf(ws[off_mc + b], 1.0f);
    float cai_p = __expf(ws[off_slp + b] / mc);
    float cai_t = __expf(ws[off_slt + b] / mc);
    float cai_l = fmaxf(cai_t - cai_p, 0.0f);
    ws[off_res + b] = 0.4f * cai_l + 0.3f * klt;
  }
}

// Kernel 3: final scalar. 1 block, B threads.
__global__ __launch_bounds__(128) void k_sum(
    const float* __restrict__ ws,
    float* __restrict__ out, int B)
{
  const int b = threadIdx.x;
  const int lane = b & 63, wave = b >> 6;
  const int off_res = 2 + 3 * B + 2 * B * 66;
  float r = (b < B) ? ws[off_res + b] : 0.0f;
  #pragma unroll
  for (int off = 32; off > 0; off >>= 1) r += __shfl_xor(r, off);
  __shared__ float sr[2];
  if (lane == 0) sr[wave] = r;
  __syncthreads();
  if (b == 0) {
    float ce = ws[0] / fmaxf(ws[1], 1.0f);
    out[0] = ce + (sr[0] + sr[1]) / (float)B;
  }
}

extern "C" void kernel_launch(void* const* d_in, const int* in_sizes, int n_in,
                              void* d_out, int out_size, void* d_ws, size_t ws_size,
                              hipStream_t stream) {
  const float* logits  = (const float*)d_in[0];
  const float* W       = (const float*)d_in[1];
  const float* refd    = (const float*)d_in[2];
  const int*   tgt     = (const int*)d_in[3];
  // d_in[4] = aa_ids: unused by the reference
  const int*   species = (const int*)d_in[5];
  const unsigned char* mask = (const unsigned char*)d_in[6];  // numpy bool = 1 byte
  float* out = (float*)d_out;
  float* ws  = (float*)d_ws;

  const int B = in_sizes[5];
  const int L = in_sizes[3] / B;       // 4096
  const int nblk = (B * L) >> 8;       // 256 positions per 1-wave block

  const int ws_words = 2 + 3 * B + 2 * B * 66 + B;
  hipMemsetAsync(d_ws, 0, (size_t)ws_words * 4, stream);

  hipLaunchKernelGGL(k_pos, dim3(nblk), dim3(64), 0, stream,
                     logits, W, tgt, species, mask, ws, B, L);
  hipLaunchKernelGGL(k_row, dim3(B), dim3(128), 0, stream,
                     refd, species, ws, B);
  hipLaunchKernelGGL(k_sum, dim3(1), dim3(128), 0, stream,
                     ws, out, B);
}